// Round 4
// baseline (162.776 us; speedup 1.0000x reference)
//
#include <hip/hip_runtime.h>
#include <math.h>

#define PI9 (2.0f * 3.14159265358979323846f / 9.0f)

typedef float f32x4 __attribute__((ext_vector_type(4)));
typedef unsigned short us8 __attribute__((ext_vector_type(8)));
typedef __bf16 bf16x8 __attribute__((ext_vector_type(8)));

__device__ __forceinline__ float ssp_f(float x) {
  const float ax = fabsf(x);
  const float t = __expf(-ax);
  return fmaxf(x, 0.f) + __logf(1.f + t) - 0.69314718f;
}

__device__ __forceinline__ unsigned short f2bf(float f) {
  unsigned int u = __float_as_uint(f);
  unsigned int r = (u + 0x7FFFu + ((u >> 16) & 1u)) >> 16;
  return (unsigned short)r;
}

// ---------------------------------------------------------------------------
// Precompute C[p,q,d] -> CT[d][p][q pad 12].  9 blocks (one per d).
// ---------------------------------------------------------------------------
__global__ __launch_bounds__(256) void precompute_C(
    const float* __restrict__ Ux_re, const float* __restrict__ Ux_im,
    const float* __restrict__ Uf_re, const float* __restrict__ Uf_im,
    const float* __restrict__ Vo_re, const float* __restrict__ Vo_im,
    float* __restrict__ CT) {
  __shared__ float G[2][729];
  __shared__ float TL[729];
  __shared__ float cs9[9], sn9[9];
  const int t0 = threadIdx.x;

  if (t0 < 9) {
    float s, c;
    __sincosf(PI9 * (float)t0, &s, &c);
    cs9[t0] = c; sn9[t0] = s;
  }
  __syncthreads();

  for (int t = t0; t < 1458; t += 256) {
    const int which = t / 729, idx = t % 729;
    const int p = idx / 81, ab = idx % 81, a = ab / 9, b = ab % 9;
    const float* Ure = which ? Uf_re : Ux_re;
    const float* Uim = which ? Uf_im : Ux_im;
    float g = 0.f;
#pragma unroll
    for (int v = 0; v < 3; ++v) {
      const int uc = v + 2;
      float hre = 0.f, him = 0.f;
#pragma unroll
      for (int ui = 0; ui < 5; ++ui) {
        const int u = (ui + 7) % 9;
        const float re = Ure[p * 25 + ui * 5 + uc];
        const float im = Uim[p * 25 + ui * 5 + uc];
        const int k = (u * a) % 9;
        const float c = cs9[k], s = sn9[k];
        hre += re * c - im * s;
        him += re * s + im * c;
      }
      hre *= (1.f / 9.f); him *= (1.f / 9.f);
      if (v == 0) {
        g += hre;
      } else {
        const int k = (v * b) % 9;
        g += 2.f * (hre * cs9[k] - him * sn9[k]);
      }
    }
    G[which][p * 81 + ab] = g * (1.f / 9.f);
  }
  __syncthreads();

  for (int t = t0; t < 729; t += 256) {
    const int ab = t / 9, d = t % 9, a = ab / 9, b = ab % 9;
    float acc = 0.f;
    for (int u = 0; u < 9; ++u)
      for (int v = 0; v < 5; ++v) {
        const int k = (u * a + v * b) % 9;
        acc += Vo_re[u * 45 + v * 9 + d] * cs9[k]
             + Vo_im[u * 45 + v * 9 + d] * sn9[k];
      }
    TL[ab * 9 + d] = acc;
  }
  __syncthreads();

  const int d = blockIdx.x;
  if (t0 < 108) {
    const int p = t0 / 12, q = t0 % 12;
    float acc = 0.f;
    if (q < 9) {
      for (int ab = 0; ab < 81; ++ab)
        acc += G[0][p * 81 + ab] * G[1][q * 81 + ab] * TL[ab * 9 + d];
    }
    CT[(d * 9 + p) * 12 + q] = acc;
  }
}

// ---------------------------------------------------------------------------
__global__ __launch_bounds__(256) void scatter_edges(
    const int* __restrict__ dst, int E, int* __restrict__ cnt,
    int* __restrict__ slots) {
  const int e = blockIdx.x * 256 + threadIdx.x;
  if (e < E) {
    const int d = dst[e];
    const int pos = atomicAdd(&cnt[d], 1);
    if (pos < 96) slots[d * 96 + pos] = e;
  }
}

// ---------------------------------------------------------------------------
// MLP via bf16 MFMA.  Block = 256 thr (4 waves), 128 edges (2 reps of 64).
// ---------------------------------------------------------------------------
__global__ __launch_bounds__(256) void mlp_mfma(
    const float* __restrict__ win, const float* __restrict__ W1,
    const float* __restrict__ W2, const float* __restrict__ W3,
    const float* __restrict__ a_w, const float* __restrict__ den,
    float* __restrict__ w48) {
  __shared__ __align__(16) float W1s[8 * 64];
  __shared__ __align__(16) unsigned short W2T[64 * 64];
  __shared__ __align__(16) unsigned short W3T[48 * 64];
  __shared__ __align__(16) unsigned short H1[4][16 * 64];
  __shared__ __align__(16) unsigned short H2[4][16 * 64];
  const int t = threadIdx.x;

  const float invden = 1.f / den[0];
  const float sc0 = a_w[0] * invden, sc1 = a_w[10] * invden, sc2 = a_w[22] * invden;
  const float rs8 = 0.35355339059327373f;

  if (t < 128) {
    float4 v = ((const float4*)W1)[t];
    v.x *= rs8; v.y *= rs8; v.z *= rs8; v.w *= rs8;
    ((float4*)W1s)[t] = v;
  }
  for (int i = t; i < 4096; i += 256) {
    const int k = i >> 6, j = i & 63;
    W2T[j * 64 + ((((k >> 3) ^ (j & 7)) << 3)) + (k & 7)] = f2bf(W2[i] * 0.125f);
  }
  for (int i = t; i < 3072; i += 256) {
    const int k = i / 48, j = i % 48;
    const int jm = j % 3;
    const float s = (jm == 0) ? sc0 : ((jm == 1) ? sc1 : sc2);
    W3T[j * 64 + ((((k >> 3) ^ (j & 7)) << 3)) + (k & 7)] = f2bf(W3[i] * 0.125f * s);
  }
  __syncthreads();

  const int w = t >> 6, l = t & 63;
  const int er = l & 15, g = l >> 4;
  unsigned short* h1p = &H1[w][0];
  unsigned short* h2p = &H2[w][0];

#pragma unroll 1
  for (int rep = 0; rep < 2; ++rep) {
    const int e = blockIdx.x * 128 + rep * 64 + w * 16 + er;

    // ---- stage 1
    float in8[8];
    {
      const float4 A = *(const float4*)(win + (size_t)e * 8);
      const float4 B = *(const float4*)(win + (size_t)e * 8 + 4);
      in8[0] = A.x; in8[1] = A.y; in8[2] = A.z; in8[3] = A.w;
      in8[4] = B.x; in8[5] = B.y; in8[6] = B.z; in8[7] = B.w;
    }
    float h[16];
#pragma unroll
    for (int c = 0; c < 16; ++c) h[c] = 0.f;
#pragma unroll
    for (int k = 0; k < 8; ++k) {
      const float* wr = &W1s[k * 64 + g * 16];
      const float4 w0 = *(const float4*)wr;
      const float4 w1 = *(const float4*)(wr + 4);
      const float4 w2 = *(const float4*)(wr + 8);
      const float4 w3 = *(const float4*)(wr + 12);
      const float ik = in8[k];
      h[0]  = fmaf(ik, w0.x, h[0]);  h[1]  = fmaf(ik, w0.y, h[1]);
      h[2]  = fmaf(ik, w0.z, h[2]);  h[3]  = fmaf(ik, w0.w, h[3]);
      h[4]  = fmaf(ik, w1.x, h[4]);  h[5]  = fmaf(ik, w1.y, h[5]);
      h[6]  = fmaf(ik, w1.z, h[6]);  h[7]  = fmaf(ik, w1.w, h[7]);
      h[8]  = fmaf(ik, w2.x, h[8]);  h[9]  = fmaf(ik, w2.y, h[9]);
      h[10] = fmaf(ik, w2.z, h[10]); h[11] = fmaf(ik, w2.w, h[11]);
      h[12] = fmaf(ik, w3.x, h[12]); h[13] = fmaf(ik, w3.y, h[13]);
      h[14] = fmaf(ik, w3.z, h[14]); h[15] = fmaf(ik, w3.w, h[15]);
    }
    us8 pk0, pk1;
#pragma unroll
    for (int jj = 0; jj < 8; ++jj) pk0[jj] = f2bf(ssp_f(h[jj]));
#pragma unroll
    for (int jj = 0; jj < 8; ++jj) pk1[jj] = f2bf(ssp_f(h[8 + jj]));
    *(us8*)&h1p[er * 64 + (((2 * g) ^ (er & 7)) << 3)] = pk0;
    *(us8*)&h1p[er * 64 + (((2 * g + 1) ^ (er & 7)) << 3)] = pk1;
    asm volatile("s_waitcnt lgkmcnt(0)" ::: "memory");
    __builtin_amdgcn_wave_barrier();

    // ---- stage 2
    const us8 a0 = *(const us8*)&h1p[er * 64 + ((g ^ (er & 7)) << 3)];
    const us8 a1 = *(const us8*)&h1p[er * 64 + (((g + 4) ^ (er & 7)) << 3)];
    float hh[16];
#pragma unroll
    for (int nt = 0; nt < 4; ++nt) {
      const int j = nt * 16 + er;
      const us8 b0 = *(const us8*)&W2T[j * 64 + ((g ^ (j & 7)) << 3)];
      const us8 b1 = *(const us8*)&W2T[j * 64 + (((g + 4) ^ (j & 7)) << 3)];
      f32x4 acc = {0.f, 0.f, 0.f, 0.f};
      acc = __builtin_amdgcn_mfma_f32_16x16x32_bf16(
          __builtin_bit_cast(bf16x8, a0), __builtin_bit_cast(bf16x8, b0), acc, 0, 0, 0);
      acc = __builtin_amdgcn_mfma_f32_16x16x32_bf16(
          __builtin_bit_cast(bf16x8, a1), __builtin_bit_cast(bf16x8, b1), acc, 0, 0, 0);
#pragma unroll
      for (int r = 0; r < 4; ++r) hh[nt * 4 + r] = ssp_f(acc[r]);
    }
#pragma unroll
    for (int nt = 0; nt < 4; ++nt)
#pragma unroll
      for (int r = 0; r < 4; ++r) {
        const int e2 = g * 4 + r;
        const int k2 = nt * 16 + er;
        h2p[e2 * 64 + ((((k2 >> 3) ^ (e2 & 7)) << 3)) + (k2 & 7)] = f2bf(hh[nt * 4 + r]);
      }
    asm volatile("s_waitcnt lgkmcnt(0)" ::: "memory");
    __builtin_amdgcn_wave_barrier();

    // ---- stage 3
    const us8 c0 = *(const us8*)&h2p[er * 64 + ((g ^ (er & 7)) << 3)];
    const us8 c1 = *(const us8*)&h2p[er * 64 + (((g + 4) ^ (er & 7)) << 3)];
    const int ebase = blockIdx.x * 128 + rep * 64 + w * 16 + g * 4;
#pragma unroll
    for (int nt = 0; nt < 3; ++nt) {
      const int o = nt * 16 + er;
      const us8 b0 = *(const us8*)&W3T[o * 64 + ((g ^ (o & 7)) << 3)];
      const us8 b1 = *(const us8*)&W3T[o * 64 + (((g + 4) ^ (o & 7)) << 3)];
      f32x4 acc = {0.f, 0.f, 0.f, 0.f};
      acc = __builtin_amdgcn_mfma_f32_16x16x32_bf16(
          __builtin_bit_cast(bf16x8, c0), __builtin_bit_cast(bf16x8, b0), acc, 0, 0, 0);
      acc = __builtin_amdgcn_mfma_f32_16x16x32_bf16(
          __builtin_bit_cast(bf16x8, c1), __builtin_bit_cast(bf16x8, b1), acc, 0, 0, 0);
#pragma unroll
      for (int r = 0; r < 4; ++r)
        w48[(size_t)(ebase + r) * 48 + o] = acc[r];
    }
    __builtin_amdgcn_wave_barrier();
  }
}

// ---------------------------------------------------------------------------
// Edge message kernel: one wave per edge (4 per block).  C from L1, filt/src
// scalarized, MeT per-wave LDS.  msg[e][m*9+d] = (x_src @ Me)[m,d] * factor.
// ---------------------------------------------------------------------------
__global__ __launch_bounds__(256) void edge_msg(
    const float* __restrict__ x, const float* __restrict__ filt,
    const int* __restrict__ src_idx, const float* __restrict__ w48,
    const float* __restrict__ CT, float* __restrict__ msg, int E) {
  __shared__ __align__(16) float MeT[4][108];
  const int t = threadIdx.x, w = t >> 6, l = t & 63;
  const int e = __builtin_amdgcn_readfirstlane(blockIdx.x * 4 + w);
  if (e >= E) return;

  const int m = l & 15, K = l >> 4;
  const int wc0 = m * 3 + ((K == 0) ? 0 : 1);
  const int wc12 = m * 3 + 2;
  const int dd0 = l / 9, p0 = l % 9;
  const int dd1 = (l + 64) / 9, p1 = (l + 64) % 9;

  const int s = __builtin_amdgcn_readfirstlane(src_idx[e]);
  float f[9];
#pragma unroll
  for (int q = 0; q < 9; ++q) f[q] = filt[(size_t)e * 9 + q];
  float xr[9];
#pragma unroll
  for (int p = 0; p < 9; ++p) xr[p] = x[(size_t)s * 144 + m * 9 + p];
  const float wv0 = w48[(size_t)e * 48 + wc0];
  const float wv12 = w48[(size_t)e * 48 + wc12];

  // Me[d][p] = sum_q CT[(d*9+p)*12+q] * f[q]
  {
    const float* c = CT + (dd0 * 9 + p0) * 12;
    const float4 ca = *(const float4*)c;
    const float4 cb = *(const float4*)(c + 4);
    float me = ca.x * f[0] + ca.y * f[1] + ca.z * f[2] + ca.w * f[3]
             + cb.x * f[4] + cb.y * f[5] + cb.z * f[6] + cb.w * f[7]
             + c[8] * f[8];
    MeT[w][dd0 * 12 + p0] = me;
  }
  if (l < 17) {
    const float* c = CT + (dd1 * 9 + p1) * 12;
    const float4 ca = *(const float4*)c;
    const float4 cb = *(const float4*)(c + 4);
    float me = ca.x * f[0] + ca.y * f[1] + ca.z * f[2] + ca.w * f[3]
             + cb.x * f[4] + cb.y * f[5] + cb.z * f[6] + cb.w * f[7]
             + c[8] * f[8];
    MeT[w][dd1 * 12 + p1] = me;
  }
  asm volatile("s_waitcnt lgkmcnt(0)" ::: "memory");
  __builtin_amdgcn_wave_barrier();

  float* mp = msg + (size_t)e * 144 + m * 9;
  {
    const float* mr = &MeT[w][K * 12];
    const float4 m0 = *(const float4*)mr;
    const float4 m1 = *(const float4*)(mr + 4);
    float v = xr[0] * m0.x + xr[1] * m0.y + xr[2] * m0.z + xr[3] * m0.w
            + xr[4] * m1.x + xr[5] * m1.y + xr[6] * m1.z + xr[7] * m1.w
            + xr[8] * mr[8];
    mp[K] = v * wv0;
  }
  {
    const float* mr = &MeT[w][(K + 4) * 12];
    const float4 m0 = *(const float4*)mr;
    const float4 m1 = *(const float4*)(mr + 4);
    float v = xr[0] * m0.x + xr[1] * m0.y + xr[2] * m0.z + xr[3] * m0.w
            + xr[4] * m1.x + xr[5] * m1.y + xr[6] * m1.z + xr[7] * m1.w
            + xr[8] * mr[8];
    mp[K + 4] = v * wv12;
  }
  if (K == 0) {
    const float* mr = &MeT[w][96];
    const float4 m0 = *(const float4*)mr;
    const float4 m1 = *(const float4*)(mr + 4);
    float v = xr[0] * m0.x + xr[1] * m0.y + xr[2] * m0.z + xr[3] * m0.w
            + xr[4] * m1.x + xr[5] * m1.y + xr[6] * m1.z + xr[7] * m1.w
            + xr[8] * mr[8];
    mp[8] = v * wv12;
  }
}

// ---------------------------------------------------------------------------
// Gather: thread per output element; 4-deep independent msg loads.
// ---------------------------------------------------------------------------
__global__ __launch_bounds__(256) void gather_kernel(
    const int* __restrict__ cnt, const int* __restrict__ slots,
    const float* __restrict__ msg, float* __restrict__ out, int total) {
  const int idx = blockIdx.x * 256 + threadIdx.x;
  if (idx >= total) return;
  const int n = idx / 144, c = idx - n * 144;
  int deg = cnt[n];
  if (deg > 96) deg = 96;
  const int* sl = slots + (size_t)n * 96;
  float acc = 0.f;
  int i = 0;
  for (; i + 4 <= deg; i += 4) {
    const int e0 = sl[i], e1 = sl[i + 1], e2 = sl[i + 2], e3 = sl[i + 3];
    const float v0 = msg[(size_t)e0 * 144 + c];
    const float v1 = msg[(size_t)e1 * 144 + c];
    const float v2 = msg[(size_t)e2 * 144 + c];
    const float v3 = msg[(size_t)e3 * 144 + c];
    acc += (v0 + v1) + (v2 + v3);
  }
  for (; i < deg; ++i) acc += msg[(size_t)sl[i] * 144 + c];
  out[idx] = acc;
}

// ---------------------------------------------------------------------------
// Fallback node kernel (round-3 structure) if ws too small for msg buffer.
// ---------------------------------------------------------------------------
__global__ __launch_bounds__(256) void node_kernel(
    const float* __restrict__ x, const float* __restrict__ filt,
    const int* __restrict__ src_idx, const int* __restrict__ cnt,
    const int* __restrict__ slots, const float* __restrict__ w48,
    const float* __restrict__ CT, float* __restrict__ out) {
  __shared__ __align__(16) float MeT[4][108];
  __shared__ __align__(16) float red[4][64][3];
  const int t = threadIdx.x, w = t >> 6, l = t & 63;
  const int n = blockIdx.x;

  int deg = cnt[n];
  if (deg > 96) deg = 96;

  const int m = l & 15, K = l >> 4;
  const int wc0 = m * 3 + ((K == 0) ? 0 : 1);
  const int wc12 = m * 3 + 2;
  const int dd0 = l / 9, p0 = l % 9;
  const int dd1 = (l + 64) / 9, p1 = (l + 64) % 9;

  float a0 = 0.f, a1 = 0.f, a2v = 0.f;

  for (int i = w; i < deg; i += 4) {
    const int e = __builtin_amdgcn_readfirstlane(slots[n * 96 + i]);
    const int s = __builtin_amdgcn_readfirstlane(src_idx[e]);
    float xr[9];
#pragma unroll
    for (int p = 0; p < 9; ++p) xr[p] = x[(size_t)s * 144 + m * 9 + p];
    float f[9];
#pragma unroll
    for (int q = 0; q < 9; ++q) f[q] = filt[(size_t)e * 9 + q];
    const float wv0 = w48[(size_t)e * 48 + wc0];
    const float wv12 = w48[(size_t)e * 48 + wc12];
    {
      const float* c = CT + (dd0 * 9 + p0) * 12;
      const float4 ca = *(const float4*)c;
      const float4 cb = *(const float4*)(c + 4);
      MeT[w][dd0 * 12 + p0] =
          ca.x * f[0] + ca.y * f[1] + ca.z * f[2] + ca.w * f[3]
        + cb.x * f[4] + cb.y * f[5] + cb.z * f[6] + cb.w * f[7] + c[8] * f[8];
    }
    if (l < 17) {
      const float* c = CT + (dd1 * 9 + p1) * 12;
      const float4 ca = *(const float4*)c;
      const float4 cb = *(const float4*)(c + 4);
      MeT[w][dd1 * 12 + p1] =
          ca.x * f[0] + ca.y * f[1] + ca.z * f[2] + ca.w * f[3]
        + cb.x * f[4] + cb.y * f[5] + cb.z * f[6] + cb.w * f[7] + c[8] * f[8];
    }
    asm volatile("s_waitcnt lgkmcnt(0)" ::: "memory");
    __builtin_amdgcn_wave_barrier();
    {
      const float* mr = &MeT[w][K * 12];
      const float4 m0 = *(const float4*)mr;
      const float4 m1 = *(const float4*)(mr + 4);
      float v = xr[0] * m0.x + xr[1] * m0.y + xr[2] * m0.z + xr[3] * m0.w
              + xr[4] * m1.x + xr[5] * m1.y + xr[6] * m1.z + xr[7] * m1.w
              + xr[8] * mr[8];
      a0 = fmaf(v, wv0, a0);
    }
    {
      const float* mr = &MeT[w][(K + 4) * 12];
      const float4 m0 = *(const float4*)mr;
      const float4 m1 = *(const float4*)(mr + 4);
      float v = xr[0] * m0.x + xr[1] * m0.y + xr[2] * m0.z + xr[3] * m0.w
              + xr[4] * m1.x + xr[5] * m1.y + xr[6] * m1.z + xr[7] * m1.w
              + xr[8] * mr[8];
      a1 = fmaf(v, wv12, a1);
    }
    if (K == 0) {
      const float* mr = &MeT[w][96];
      const float4 m0 = *(const float4*)mr;
      const float4 m1 = *(const float4*)(mr + 4);
      float v = xr[0] * m0.x + xr[1] * m0.y + xr[2] * m0.z + xr[3] * m0.w
              + xr[4] * m1.x + xr[5] * m1.y + xr[6] * m1.z + xr[7] * m1.w
              + xr[8] * mr[8];
      a2v = fmaf(v, wv12, a2v);
    }
    __builtin_amdgcn_wave_barrier();
  }

  red[w][l][0] = a0;
  red[w][l][1] = a1;
  red[w][l][2] = a2v;
  __syncthreads();

  if (t < 144) {
    const int mm = t / 9, d = t % 9;
    int lane, slot;
    if (d < 4)      { lane = d * 16 + mm;       slot = 0; }
    else if (d < 8) { lane = (d - 4) * 16 + mm; slot = 1; }
    else            { lane = mm;                slot = 2; }
    out[(size_t)n * 144 + t] = red[0][lane][slot] + red[1][lane][slot]
                             + red[2][lane][slot] + red[3][lane][slot];
  }
}

// ---------------------------------------------------------------------------
extern "C" void kernel_launch(void* const* d_in, const int* in_sizes, int n_in,
                              void* d_out, int out_size, void* d_ws, size_t ws_size,
                              hipStream_t stream) {
  const float* x      = (const float*)d_in[0];
  const float* filt   = (const float*)d_in[1];
  const float* win    = (const float*)d_in[2];
  const int*   eidx   = (const int*)d_in[3];
  const float* Ux_re  = (const float*)d_in[4];
  const float* Ux_im  = (const float*)d_in[5];
  const float* Uf_re  = (const float*)d_in[6];
  const float* Uf_im  = (const float*)d_in[7];
  const float* Vo_re  = (const float*)d_in[8];
  const float* Vo_im  = (const float*)d_in[9];
  const float* W1     = (const float*)d_in[10];
  const float* W2     = (const float*)d_in[11];
  const float* W3     = (const float*)d_in[12];
  const float* a_w    = (const float*)d_in[13];
  const float* den    = (const float*)d_in[14];
  float* out = (float*)d_out;

  const int N = in_sizes[0] / 144;          // 10000
  const int E = in_sizes[3] / 2;            // 160000
  const int* dst = eidx;
  const int* src = eidx + E;

  char* wsb = (char*)d_ws;
  const size_t off_cnt  = 4096;
  const size_t off_slot = off_cnt + 40960;
  const size_t off_w48  = off_slot + (size_t)N * 96 * 4;
  const size_t off_msg  = off_w48 + (size_t)E * 48 * 4;
  const size_t need     = off_msg + (size_t)E * 144 * 4;

  float* CT   = (float*)wsb;
  int*   cnt  = (int*)(wsb + off_cnt);
  int*   slot = (int*)(wsb + off_slot);
  float* w48  = (float*)(wsb + off_w48);
  float* msg  = (float*)(wsb + off_msg);

  hipMemsetAsync(cnt, 0, (size_t)N * sizeof(int), stream);
  precompute_C<<<9, 256, 0, stream>>>(Ux_re, Ux_im, Uf_re, Uf_im, Vo_re, Vo_im, CT);
  scatter_edges<<<(E + 255) / 256, 256, 0, stream>>>(dst, E, cnt, slot);
  mlp_mfma<<<E / 128, 256, 0, stream>>>(win, W1, W2, W3, a_w, den, w48);

  if (ws_size >= need) {
    edge_msg<<<(E + 3) / 4, 256, 0, stream>>>(x, filt, src, w48, CT, msg, E);
    const int total = N * 144;
    gather_kernel<<<(total + 255) / 256, 256, 0, stream>>>(cnt, slot, msg, out, total);
  } else {
    node_kernel<<<N, 256, 0, stream>>>(x, filt, src, cnt, slot, w48, CT, out);
  }
}

// Round 5
// 123.656 us; speedup vs baseline: 1.3164x; 1.3164x over previous
//
#include <hip/hip_runtime.h>
#include <math.h>

#define PI9 (2.0f * 3.14159265358979323846f / 9.0f)

typedef float f32x4 __attribute__((ext_vector_type(4)));
typedef unsigned short us8 __attribute__((ext_vector_type(8)));
typedef __bf16 bf16x8 __attribute__((ext_vector_type(8)));

__device__ __forceinline__ float ssp_f(float x) {
  const float ax = fabsf(x);
  const float t = __expf(-ax);
  return fmaxf(x, 0.f) + __logf(1.f + t) - 0.69314718f;
}

__device__ __forceinline__ unsigned short f2bf(float f) {
  unsigned int u = __float_as_uint(f);
  unsigned int r = (u + 0x7FFFu + ((u >> 16) & 1u)) >> 16;
  return (unsigned short)r;
}

// ---------------------------------------------------------------------------
// Precompute C[p,q,d] -> CT[d][p][q pad 12].  9 blocks (one per d).
// ---------------------------------------------------------------------------
__global__ __launch_bounds__(256) void precompute_C(
    const float* __restrict__ Ux_re, const float* __restrict__ Ux_im,
    const float* __restrict__ Uf_re, const float* __restrict__ Uf_im,
    const float* __restrict__ Vo_re, const float* __restrict__ Vo_im,
    float* __restrict__ CT) {
  __shared__ float G[2][729];
  __shared__ float TL[729];
  __shared__ float cs9[9], sn9[9];
  const int t0 = threadIdx.x;

  if (t0 < 9) {
    float s, c;
    __sincosf(PI9 * (float)t0, &s, &c);
    cs9[t0] = c; sn9[t0] = s;
  }
  __syncthreads();

  for (int t = t0; t < 1458; t += 256) {
    const int which = t / 729, idx = t % 729;
    const int p = idx / 81, ab = idx % 81, a = ab / 9, b = ab % 9;
    const float* Ure = which ? Uf_re : Ux_re;
    const float* Uim = which ? Uf_im : Ux_im;
    float g = 0.f;
#pragma unroll
    for (int v = 0; v < 3; ++v) {
      const int uc = v + 2;
      float hre = 0.f, him = 0.f;
#pragma unroll
      for (int ui = 0; ui < 5; ++ui) {
        const int u = (ui + 7) % 9;
        const float re = Ure[p * 25 + ui * 5 + uc];
        const float im = Uim[p * 25 + ui * 5 + uc];
        const int k = (u * a) % 9;
        const float c = cs9[k], s = sn9[k];
        hre += re * c - im * s;
        him += re * s + im * c;
      }
      hre *= (1.f / 9.f); him *= (1.f / 9.f);
      if (v == 0) {
        g += hre;
      } else {
        const int k = (v * b) % 9;
        g += 2.f * (hre * cs9[k] - him * sn9[k]);
      }
    }
    G[which][p * 81 + ab] = g * (1.f / 9.f);
  }
  __syncthreads();

  for (int t = t0; t < 729; t += 256) {
    const int ab = t / 9, d = t % 9, a = ab / 9, b = ab % 9;
    float acc = 0.f;
    for (int u = 0; u < 9; ++u)
      for (int v = 0; v < 5; ++v) {
        const int k = (u * a + v * b) % 9;
        acc += Vo_re[u * 45 + v * 9 + d] * cs9[k]
             + Vo_im[u * 45 + v * 9 + d] * sn9[k];
      }
    TL[ab * 9 + d] = acc;
  }
  __syncthreads();

  const int d = blockIdx.x;
  if (t0 < 108) {
    const int p = t0 / 12, q = t0 % 12;
    float acc = 0.f;
    if (q < 9) {
      for (int ab = 0; ab < 81; ++ab)
        acc += G[0][p * 81 + ab] * G[1][q * 81 + ab] * TL[ab * 9 + d];
    }
    CT[(d * 9 + p) * 12 + q] = acc;
  }
}

// ---------------------------------------------------------------------------
__global__ __launch_bounds__(256) void scatter_edges(
    const int* __restrict__ dst, int E, int* __restrict__ cnt,
    int* __restrict__ slots) {
  const int e = blockIdx.x * 256 + threadIdx.x;
  if (e < E) {
    const int d = dst[e];
    const int pos = atomicAdd(&cnt[d], 1);
    if (pos < 96) slots[d * 96 + pos] = e;
  }
}

// ---------------------------------------------------------------------------
// MLP via bf16 MFMA.  Block = 256 thr (4 waves), 128 edges (2 reps of 64).
// ---------------------------------------------------------------------------
__global__ __launch_bounds__(256) void mlp_mfma(
    const float* __restrict__ win, const float* __restrict__ W1,
    const float* __restrict__ W2, const float* __restrict__ W3,
    const float* __restrict__ a_w, const float* __restrict__ den,
    float* __restrict__ w48) {
  __shared__ __align__(16) float W1s[8 * 64];
  __shared__ __align__(16) unsigned short W2T[64 * 64];
  __shared__ __align__(16) unsigned short W3T[48 * 64];
  __shared__ __align__(16) unsigned short H1[4][16 * 64];
  __shared__ __align__(16) unsigned short H2[4][16 * 64];
  const int t = threadIdx.x;

  const float invden = 1.f / den[0];
  const float sc0 = a_w[0] * invden, sc1 = a_w[10] * invden, sc2 = a_w[22] * invden;
  const float rs8 = 0.35355339059327373f;

  if (t < 128) {
    float4 v = ((const float4*)W1)[t];
    v.x *= rs8; v.y *= rs8; v.z *= rs8; v.w *= rs8;
    ((float4*)W1s)[t] = v;
  }
  for (int i = t; i < 4096; i += 256) {
    const int k = i >> 6, j = i & 63;
    W2T[j * 64 + ((((k >> 3) ^ (j & 7)) << 3)) + (k & 7)] = f2bf(W2[i] * 0.125f);
  }
  for (int i = t; i < 3072; i += 256) {
    const int k = i / 48, j = i % 48;
    const int jm = j % 3;
    const float s = (jm == 0) ? sc0 : ((jm == 1) ? sc1 : sc2);
    W3T[j * 64 + ((((k >> 3) ^ (j & 7)) << 3)) + (k & 7)] = f2bf(W3[i] * 0.125f * s);
  }
  __syncthreads();

  const int w = t >> 6, l = t & 63;
  const int er = l & 15, g = l >> 4;
  unsigned short* h1p = &H1[w][0];
  unsigned short* h2p = &H2[w][0];

#pragma unroll 1
  for (int rep = 0; rep < 2; ++rep) {
    const int e = blockIdx.x * 128 + rep * 64 + w * 16 + er;

    // ---- stage 1
    float in8[8];
    {
      const float4 A = *(const float4*)(win + (size_t)e * 8);
      const float4 B = *(const float4*)(win + (size_t)e * 8 + 4);
      in8[0] = A.x; in8[1] = A.y; in8[2] = A.z; in8[3] = A.w;
      in8[4] = B.x; in8[5] = B.y; in8[6] = B.z; in8[7] = B.w;
    }
    float h[16];
#pragma unroll
    for (int c = 0; c < 16; ++c) h[c] = 0.f;
#pragma unroll
    for (int k = 0; k < 8; ++k) {
      const float* wr = &W1s[k * 64 + g * 16];
      const float4 w0 = *(const float4*)wr;
      const float4 w1 = *(const float4*)(wr + 4);
      const float4 w2 = *(const float4*)(wr + 8);
      const float4 w3 = *(const float4*)(wr + 12);
      const float ik = in8[k];
      h[0]  = fmaf(ik, w0.x, h[0]);  h[1]  = fmaf(ik, w0.y, h[1]);
      h[2]  = fmaf(ik, w0.z, h[2]);  h[3]  = fmaf(ik, w0.w, h[3]);
      h[4]  = fmaf(ik, w1.x, h[4]);  h[5]  = fmaf(ik, w1.y, h[5]);
      h[6]  = fmaf(ik, w1.z, h[6]);  h[7]  = fmaf(ik, w1.w, h[7]);
      h[8]  = fmaf(ik, w2.x, h[8]);  h[9]  = fmaf(ik, w2.y, h[9]);
      h[10] = fmaf(ik, w2.z, h[10]); h[11] = fmaf(ik, w2.w, h[11]);
      h[12] = fmaf(ik, w3.x, h[12]); h[13] = fmaf(ik, w3.y, h[13]);
      h[14] = fmaf(ik, w3.z, h[14]); h[15] = fmaf(ik, w3.w, h[15]);
    }
    us8 pk0, pk1;
#pragma unroll
    for (int jj = 0; jj < 8; ++jj) pk0[jj] = f2bf(ssp_f(h[jj]));
#pragma unroll
    for (int jj = 0; jj < 8; ++jj) pk1[jj] = f2bf(ssp_f(h[8 + jj]));
    *(us8*)&h1p[er * 64 + (((2 * g) ^ (er & 7)) << 3)] = pk0;
    *(us8*)&h1p[er * 64 + (((2 * g + 1) ^ (er & 7)) << 3)] = pk1;
    __builtin_amdgcn_wave_barrier();

    // ---- stage 2
    const us8 a0 = *(const us8*)&h1p[er * 64 + ((g ^ (er & 7)) << 3)];
    const us8 a1 = *(const us8*)&h1p[er * 64 + (((g + 4) ^ (er & 7)) << 3)];
    float hh[16];
#pragma unroll
    for (int nt = 0; nt < 4; ++nt) {
      const int j = nt * 16 + er;
      const us8 b0 = *(const us8*)&W2T[j * 64 + ((g ^ (j & 7)) << 3)];
      const us8 b1 = *(const us8*)&W2T[j * 64 + (((g + 4) ^ (j & 7)) << 3)];
      f32x4 acc = {0.f, 0.f, 0.f, 0.f};
      acc = __builtin_amdgcn_mfma_f32_16x16x32_bf16(
          __builtin_bit_cast(bf16x8, a0), __builtin_bit_cast(bf16x8, b0), acc, 0, 0, 0);
      acc = __builtin_amdgcn_mfma_f32_16x16x32_bf16(
          __builtin_bit_cast(bf16x8, a1), __builtin_bit_cast(bf16x8, b1), acc, 0, 0, 0);
#pragma unroll
      for (int r = 0; r < 4; ++r) hh[nt * 4 + r] = ssp_f(acc[r]);
    }
#pragma unroll
    for (int nt = 0; nt < 4; ++nt)
#pragma unroll
      for (int r = 0; r < 4; ++r) {
        const int e2 = g * 4 + r;
        const int k2 = nt * 16 + er;
        h2p[e2 * 64 + ((((k2 >> 3) ^ (e2 & 7)) << 3)) + (k2 & 7)] = f2bf(hh[nt * 4 + r]);
      }
    __builtin_amdgcn_wave_barrier();

    // ---- stage 3
    const us8 c0 = *(const us8*)&h2p[er * 64 + ((g ^ (er & 7)) << 3)];
    const us8 c1 = *(const us8*)&h2p[er * 64 + (((g + 4) ^ (er & 7)) << 3)];
    const int ebase = blockIdx.x * 128 + rep * 64 + w * 16 + g * 4;
#pragma unroll
    for (int nt = 0; nt < 3; ++nt) {
      const int o = nt * 16 + er;
      const us8 b0 = *(const us8*)&W3T[o * 64 + ((g ^ (o & 7)) << 3)];
      const us8 b1 = *(const us8*)&W3T[o * 64 + (((g + 4) ^ (o & 7)) << 3)];
      f32x4 acc = {0.f, 0.f, 0.f, 0.f};
      acc = __builtin_amdgcn_mfma_f32_16x16x32_bf16(
          __builtin_bit_cast(bf16x8, c0), __builtin_bit_cast(bf16x8, b0), acc, 0, 0, 0);
      acc = __builtin_amdgcn_mfma_f32_16x16x32_bf16(
          __builtin_bit_cast(bf16x8, c1), __builtin_bit_cast(bf16x8, b1), acc, 0, 0, 0);
#pragma unroll
      for (int r = 0; r < 4; ++r)
        w48[(size_t)(ebase + r) * 48 + o] = acc[r];
    }
    __builtin_amdgcn_wave_barrier();
  }
}

// ---------------------------------------------------------------------------
// Node kernel v4: fused, slim.  4 waves/node, 1 edge/wave/iter.
//  - C rows hoisted to VGPRs (one-time L1 loads)
//  - x staged via 36-lane coalesced float4 -> PADDED LDS rows (m*12+p)
//  - Me per-wave LDS [9][12]; DS in-order per wave => wave_barrier only
//  - 1-deep prefetch of next edge's scalars/vectors
// ---------------------------------------------------------------------------
__global__ __launch_bounds__(256) void node_kernel(
    const float* __restrict__ x, const float* __restrict__ filt,
    const int* __restrict__ src_idx, const int* __restrict__ cnt,
    const int* __restrict__ slots, const float* __restrict__ w48,
    const float* __restrict__ CT, float* __restrict__ out) {
  __shared__ __align__(16) float xsl[4][16 * 12];   // [m][p pad 12]
  __shared__ __align__(16) float MeT[4][9 * 12];    // [d][p pad 12]
  __shared__ __align__(16) float red[4][64][3];
  const int t = threadIdx.x, w = t >> 6, l = t & 63;
  const int n = blockIdx.x;

  int deg = cnt[n];
  if (deg > 96) deg = 96;

  const int m = l & 15, K = l >> 4;
  const int wc0 = m * 3 + ((K == 0) ? 0 : 1);
  const int wc12 = m * 3 + 2;
  const int dd0 = l / 9, p0 = l % 9;
  const int dd1 = (l + 64) / 9, p1 = (l + 64) % 9;

  // x-stage write addresses (lane-constant, padded layout)
  int wa[4];
  {
    const int j0 = l * 4;
    const int m0 = j0 / 9, q0 = j0 - m0 * 9;
#pragma unroll
    for (int c = 0; c < 4; ++c) {
      const int jj = j0 + c;
      const int mm = jj / 9, qq = jj - mm * 9;
      wa[c] = mm * 12 + qq;
    }
    (void)m0; (void)q0;
  }

  // hoisted C rows (CT is ~4 KB, L1/L2-resident; OOB-safe inside ws)
  const float* c0p = CT + (dd0 * 9 + p0) * 12;
  const float4 C0a = *(const float4*)c0p;
  const float4 C0b = *(const float4*)(c0p + 4);
  const float  C0c = c0p[8];
  const float* c1p = CT + (dd1 * 9 + p1) * 12;
  const float4 C1a = *(const float4*)c1p;
  const float4 C1b = *(const float4*)(c1p + 4);
  const float  C1c = c1p[8];

  float a0 = 0.f, a1 = 0.f, a2v = 0.f;

  int i = w;
  if (i < deg) {
    int e = __builtin_amdgcn_readfirstlane(slots[n * 96 + i]);
    int s = __builtin_amdgcn_readfirstlane(src_idx[e]);
    float f[9];
#pragma unroll
    for (int q = 0; q < 9; ++q) f[q] = filt[(size_t)e * 9 + q];
    float4 xv = make_float4(0.f, 0.f, 0.f, 0.f);
    if (l < 36) xv = *(const float4*)(x + (size_t)s * 144 + l * 4);
    float wv0 = w48[(size_t)e * 48 + wc0];
    float wv12 = w48[(size_t)e * 48 + wc12];

    while (true) {
      // stage x (padded) + build Me
      if (l < 36) {
        xsl[w][wa[0]] = xv.x;
        xsl[w][wa[1]] = xv.y;
        xsl[w][wa[2]] = xv.z;
        xsl[w][wa[3]] = xv.w;
      }
      {
        float me = f[0] * C0a.x;
        me = fmaf(f[1], C0a.y, me); me = fmaf(f[2], C0a.z, me);
        me = fmaf(f[3], C0a.w, me); me = fmaf(f[4], C0b.x, me);
        me = fmaf(f[5], C0b.y, me); me = fmaf(f[6], C0b.z, me);
        me = fmaf(f[7], C0b.w, me); me = fmaf(f[8], C0c, me);
        MeT[w][dd0 * 12 + p0] = me;
      }
      if (l < 17) {
        float me = f[0] * C1a.x;
        me = fmaf(f[1], C1a.y, me); me = fmaf(f[2], C1a.z, me);
        me = fmaf(f[3], C1a.w, me); me = fmaf(f[4], C1b.x, me);
        me = fmaf(f[5], C1b.y, me); me = fmaf(f[6], C1b.z, me);
        me = fmaf(f[7], C1b.w, me); me = fmaf(f[8], C1c, me);
        MeT[w][dd1 * 12 + p1] = me;
      }

      // prefetch next edge
      const int inext = i + 4;
      const bool more = inext < deg;
      float4 xv_n = make_float4(0.f, 0.f, 0.f, 0.f);
      float f_n[9];
      float wn0 = 0.f, wn12 = 0.f;
      if (more) {
        const int e_n = __builtin_amdgcn_readfirstlane(slots[n * 96 + inext]);
        const int s_n = __builtin_amdgcn_readfirstlane(src_idx[e_n]);
        if (l < 36) xv_n = *(const float4*)(x + (size_t)s_n * 144 + l * 4);
#pragma unroll
        for (int q = 0; q < 9; ++q) f_n[q] = filt[(size_t)e_n * 9 + q];
        wn0 = w48[(size_t)e_n * 48 + wc0];
        wn12 = w48[(size_t)e_n * 48 + wc12];
      } else {
#pragma unroll
        for (int q = 0; q < 9; ++q) f_n[q] = 0.f;
      }

      __builtin_amdgcn_wave_barrier();   // DS pipe in-order: write->read safe

      // read x row (aligned b128, 2-way-free banks) and Me rows
      const float* xr = &xsl[w][m * 12];
      const float4 x0 = *(const float4*)xr;
      const float4 x1 = *(const float4*)(xr + 4);
      const float  x8 = xr[8];
      {
        const float* mr = &MeT[w][K * 12];
        const float4 m0 = *(const float4*)mr;
        const float4 m1 = *(const float4*)(mr + 4);
        float v = x0.x * m0.x + x0.y * m0.y + x0.z * m0.z + x0.w * m0.w
                + x1.x * m1.x + x1.y * m1.y + x1.z * m1.z + x1.w * m1.w
                + x8 * mr[8];
        a0 = fmaf(v, wv0, a0);
      }
      {
        const float* mr = &MeT[w][(K + 4) * 12];
        const float4 m0 = *(const float4*)mr;
        const float4 m1 = *(const float4*)(mr + 4);
        float v = x0.x * m0.x + x0.y * m0.y + x0.z * m0.z + x0.w * m0.w
                + x1.x * m1.x + x1.y * m1.y + x1.z * m1.z + x1.w * m1.w
                + x8 * mr[8];
        a1 = fmaf(v, wv12, a1);
      }
      if (K == 0) {
        const float* mr = &MeT[w][8 * 12];
        const float4 m0 = *(const float4*)mr;
        const float4 m1 = *(const float4*)(mr + 4);
        float v = x0.x * m0.x + x0.y * m0.y + x0.z * m0.z + x0.w * m0.w
                + x1.x * m1.x + x1.y * m1.y + x1.z * m1.z + x1.w * m1.w
                + x8 * mr[8];
        a2v = fmaf(v, wv12, a2v);
      }
      __builtin_amdgcn_wave_barrier();   // before next iter overwrites LDS

      if (!more) break;
      i = inext;
      xv = xv_n;
#pragma unroll
      for (int q = 0; q < 9; ++q) f[q] = f_n[q];
      wv0 = wn0; wv12 = wn12;
    }
  }

  red[w][l][0] = a0;
  red[w][l][1] = a1;
  red[w][l][2] = a2v;
  __syncthreads();

  if (t < 144) {
    const int mm = t / 9, d = t % 9;
    int lane, slot;
    if (d < 4)      { lane = d * 16 + mm;       slot = 0; }
    else if (d < 8) { lane = (d - 4) * 16 + mm; slot = 1; }
    else            { lane = mm;                slot = 2; }
    out[(size_t)n * 144 + t] = red[0][lane][slot] + red[1][lane][slot]
                             + red[2][lane][slot] + red[3][lane][slot];
  }
}

// ---------------------------------------------------------------------------
extern "C" void kernel_launch(void* const* d_in, const int* in_sizes, int n_in,
                              void* d_out, int out_size, void* d_ws, size_t ws_size,
                              hipStream_t stream) {
  const float* x      = (const float*)d_in[0];
  const float* filt   = (const float*)d_in[1];
  const float* win    = (const float*)d_in[2];
  const int*   eidx   = (const int*)d_in[3];
  const float* Ux_re  = (const float*)d_in[4];
  const float* Ux_im  = (const float*)d_in[5];
  const float* Uf_re  = (const float*)d_in[6];
  const float* Uf_im  = (const float*)d_in[7];
  const float* Vo_re  = (const float*)d_in[8];
  const float* Vo_im  = (const float*)d_in[9];
  const float* W1     = (const float*)d_in[10];
  const float* W2     = (const float*)d_in[11];
  const float* W3     = (const float*)d_in[12];
  const float* a_w    = (const float*)d_in[13];
  const float* den    = (const float*)d_in[14];
  float* out = (float*)d_out;

  const int N = in_sizes[0] / 144;          // 10000
  const int E = in_sizes[3] / 2;            // 160000
  const int* dst = eidx;
  const int* src = eidx + E;

  char* wsb = (char*)d_ws;
  float* CT   = (float*)wsb;                                  // 972 f (+pad)
  int*   cnt  = (int*)(wsb + 8192);                           // N ints
  int*   slot = (int*)(wsb + 8192 + 40960);                   // N*96 ints
  float* w48  = (float*)(wsb + 8192 + 40960 + (size_t)N * 96 * 4);

  hipMemsetAsync(cnt, 0, (size_t)N * sizeof(int), stream);
  precompute_C<<<9, 256, 0, stream>>>(Ux_re, Ux_im, Uf_re, Uf_im, Vo_re, Vo_im, CT);
  scatter_edges<<<(E + 255) / 256, 256, 0, stream>>>(dst, E, cnt, slot);
  mlp_mfma<<<E / 128, 256, 0, stream>>>(win, W1, W2, W3, a_w, den, w48);
  node_kernel<<<N, 256, 0, stream>>>(x, filt, src, cnt, slot, w48, CT, out);
}